// Round 4
// baseline (400.912 us; speedup 1.0000x reference)
//
#include <hip/hip_runtime.h>

// MHA: B=2, S=2048, D=1024, H=16, DK=64. Output/input float dtype is either
// bf16 or fp32 (harness ambiguity) -> runtime-detected, dual-path loads/stores.
// mask is int32.
//
// Pipeline (ws: 16 MB + 64 B flag; d_out doubles as V scratch):
//   0) detect: classify d_in[0] as bf16-packed or fp32 -> flag in ws
//   1) gemm3<0>: Q/K/V proj y = x @ W^T -> head-split [B,H,S,DK] bf16
//        Qh -> ws[0:8M), Kh -> ws[8M:16M), Vh -> d_out (dead after attn)
//   2) attn: flash online softmax -> ctx head-split IN PLACE over Qh
//        (block (bh,qb) reads only its own 64 Q rows pre-loop, writes exactly
//         those rows at the end -> race-free)
//   3) gemm3<1>: out = ctx @ Wo^T -> d_out (bf16 or fp32 per flag)
//
// MFMA 16x16x32 bf16 layouts (verified, cdna_hip_programming.md §3):
//   A: lane holds A[m=lane&15][k=(lane>>4)*8+j], j=0..7
//   B: lane holds B[k=(lane>>4)*8+j][n=lane&15]
//   C/D: col=lane&15, row=(lane>>4)*4+reg
//
// R3 lessons: all data accesses are now type-consistent __bf16 (no u16/bf16
// TBAA punning); external loads/stores are dtype-dual.

typedef __bf16 bf16x8 __attribute__((ext_vector_type(8)));
typedef float f32x4 __attribute__((ext_vector_type(4)));

#define B_ 2
#define S_ 2048
#define D_ 1024
#define H_ 16
#define DK_ 64

// ---------------------------------------------------------------------------
// dtype detection: one wave samples 256 u32 words of q. If the LOW 16 bits of
// a word are a plausible N(0,1) bf16 (exponent in [100,140]), count it.
// bf16-packed input -> ~256/256 plausible; fp32 input (low bits = mantissa
// junk) -> ~41/256. flag = 1 means fp32.
// ---------------------------------------------------------------------------
__global__ void detect_dtype(const unsigned int* __restrict__ qw,
                             int* __restrict__ flag) {
  int cnt = 0;
#pragma unroll
  for (int i = 0; i < 4; ++i) {
    unsigned int w = qw[threadIdx.x + 64 * i];
    int e = (w >> 7) & 0xFF;
    cnt += (e >= 100 && e <= 140) ? 1 : 0;
  }
#pragma unroll
  for (int off = 32; off > 0; off >>= 1) cnt += __shfl_down(cnt, off, 64);
  if (threadIdx.x == 0) *flag = (cnt >= 128) ? 0 : 1;
}

// 8 contiguous elements at element-offset eoff of an external float tensor,
// as bf16 (passthrough or fp32->bf16 convert).
__device__ __forceinline__ bf16x8 load8cvt(const void* base, size_t eoff,
                                           bool f32) {
  if (!f32) return *(const bf16x8*)((const __bf16*)base + eoff);
  const float* p = (const float*)base + eoff;
  bf16x8 r;
#pragma unroll
  for (int j = 0; j < 8; ++j) r[j] = (__bf16)p[j];
  return r;
}

// ---------------------------------------------------------------------------
// GEMM: C[M,N] = X[M,K] @ W[N,K]^T, M=4096, N=K=1024.
// 128x128 tile, 4 waves (2x2 of 64x64), BK=32, LDS rows padded to 40 elems.
// MODE 0: X external (dual dtype) row-major, O bf16 head-split [B,H,S,DK].
// MODE 1: X internal bf16 head-split,        O external (dual dtype) [M,N].
// W always external (dual dtype). blockIdx.z picks the (X,W,O) triple.
// ---------------------------------------------------------------------------
template <int MODE>
__global__ __launch_bounds__(256) void gemm3(
    const void* X0, const void* X1, const void* X2,
    const void* W0, const void* W1, const void* W2,
    void* O0, void* O1, void* O2, const int* __restrict__ dflag) {
  constexpr int Kd = 1024, Nd = 1024;
  const void* X = (blockIdx.z == 0) ? X0 : (blockIdx.z == 1 ? X1 : X2);
  const void* W = (blockIdx.z == 0) ? W0 : (blockIdx.z == 1 ? W1 : W2);
  void* O = (blockIdx.z == 0) ? O0 : (blockIdx.z == 1 ? O1 : O2);
  const bool f32io = (*dflag != 0);

  __shared__ __attribute__((aligned(16))) __bf16 As[128][40];
  __shared__ __attribute__((aligned(16))) __bf16 Bs[128][40];

  const int m0 = blockIdx.x * 128;
  const int n0 = blockIdx.y * 128;
  const int t = threadIdx.x;
  const int lane = t & 63, wave = t >> 6;
  const int wm = (wave >> 1) * 64, wn = (wave & 1) * 64;
  const int l15 = lane & 15, quad = lane >> 4;

  f32x4 acc[4][4] = {};

  for (int k0 = 0; k0 < Kd; k0 += 32) {
    __syncthreads();
#pragma unroll
    for (int i = 0; i < 2; ++i) {
      int slot = t + 256 * i;
      int row = slot >> 2, c8 = (slot & 3) * 8;
      bf16x8 xv;
      if (MODE == 0) {
        xv = load8cvt(X, (size_t)(m0 + row) * Kd + k0 + c8, f32io);
      } else {
        int gm = m0 + row, gk = k0 + c8;  // gk stays within one head (c8 mult of 8)
        size_t off = ((((size_t)(gm >> 11) * H_ + (gk >> 6)) * S_) +
                      (gm & (S_ - 1))) * DK_ + (gk & (DK_ - 1));
        xv = *(const bf16x8*)((const __bf16*)X + off);
      }
      bf16x8 wv = load8cvt(W, (size_t)(n0 + row) * Kd + k0 + c8, f32io);
      *(bf16x8*)&As[row][c8] = xv;
      *(bf16x8*)&Bs[row][c8] = wv;
    }
    __syncthreads();

    bf16x8 af[4], bfr[4];
#pragma unroll
    for (int mi = 0; mi < 4; ++mi)
      af[mi] = *(const bf16x8*)&As[wm + mi * 16 + l15][quad * 8];
#pragma unroll
    for (int ni = 0; ni < 4; ++ni)
      bfr[ni] = *(const bf16x8*)&Bs[wn + ni * 16 + l15][quad * 8];
#pragma unroll
    for (int mi = 0; mi < 4; ++mi)
#pragma unroll
      for (int ni = 0; ni < 4; ++ni)
        acc[mi][ni] = __builtin_amdgcn_mfma_f32_16x16x32_bf16(af[mi], bfr[ni],
                                                              acc[mi][ni], 0, 0, 0);
  }

#pragma unroll
  for (int mi = 0; mi < 4; ++mi) {
#pragma unroll
    for (int ni = 0; ni < 4; ++ni) {
#pragma unroll
      for (int r = 0; r < 4; ++r) {
        int m = m0 + wm + mi * 16 + quad * 4 + r;
        int n = n0 + wn + ni * 16 + l15;
        float val = acc[mi][ni][r];
        if (MODE == 0) {
          int b = m >> 11, s = m & (S_ - 1);
          int h = n >> 6, dk = n & (DK_ - 1);
          ((__bf16*)O)[(((size_t)(b * H_ + h) * S_) + s) * DK_ + dk] = (__bf16)val;
        } else {
          size_t idx = (size_t)m * Nd + n;
          if (f32io) ((float*)O)[idx] = val;
          else       ((__bf16*)O)[idx] = (__bf16)val;
        }
      }
    }
  }
}

// ---------------------------------------------------------------------------
// Flash attention (all-bf16 internal). One block = one (b,h) x 64 q-rows; each
// of 4 waves owns 16 q-rows. Keys 32 at a time: 2 score MFMAs, fp32 online
// softmax (shfl-xor width 16 over keys), P via LDS (C-layout -> A-layout,
// fenced), 4 PV MFMAs. ctx written head-split IN PLACE over Qh (no __restrict
// on Qh/Out).
// ---------------------------------------------------------------------------
__global__ __launch_bounds__(256) void attn(
    const __bf16* Qh, const __bf16* __restrict__ Kh,
    const __bf16* __restrict__ Vh, const int* __restrict__ mask,
    __bf16* Out) {
  __shared__ __attribute__((aligned(16))) __bf16 P[4][16][32];

  const int t = threadIdx.x;
  const int lane = t & 63, wave = t >> 6;
  const int l15 = lane & 15, quad = lane >> 4;
  const int qb = blockIdx.x & 31;   // S/64 = 32 q-blocks
  const int bh = blockIdx.x >> 5;   // b*H + h
  const int b = bh >> 4;
  const int q0 = qb * 64 + wave * 16;

  const __bf16* Q = Qh + (size_t)bh * S_ * DK_;
  const __bf16* K = Kh + (size_t)bh * S_ * DK_;
  const __bf16* V = Vh + (size_t)bh * S_ * DK_;
  const int* mk = mask + b * S_;

  bf16x8 qf0 = *(const bf16x8*)&Q[(q0 + l15) * DK_ + quad * 8];
  bf16x8 qf1 = *(const bf16x8*)&Q[(q0 + l15) * DK_ + 32 + quad * 8];

  f32x4 o[4] = {};
  float mrow[4], lrow[4];
#pragma unroll
  for (int r = 0; r < 4; ++r) { mrow[r] = -1e30f; lrow[r] = 0.f; }

  for (int kb = 0; kb < S_; kb += 32) {
    f32x4 s[2];
#pragma unroll
    for (int tt = 0; tt < 2; ++tt) {
      bf16x8 kf0 = *(const bf16x8*)&K[(kb + tt * 16 + l15) * DK_ + quad * 8];
      bf16x8 kf1 = *(const bf16x8*)&K[(kb + tt * 16 + l15) * DK_ + 32 + quad * 8];
      f32x4 z = {};
      z = __builtin_amdgcn_mfma_f32_16x16x32_bf16(qf0, kf0, z, 0, 0, 0);
      z = __builtin_amdgcn_mfma_f32_16x16x32_bf16(qf1, kf1, z, 0, 0, 0);
      s[tt] = z;
    }
    const int mv0 = mk[kb + l15];
    const int mv1 = mk[kb + 16 + l15];
#pragma unroll
    for (int r = 0; r < 4; ++r) {
      s[0][r] = mv0 ? s[0][r] * 0.125f : -1e9f;
      s[1][r] = mv1 ? s[1][r] * 0.125f : -1e9f;
    }

    float alpha[4];
#pragma unroll
    for (int r = 0; r < 4; ++r) {
      float mx = fmaxf(s[0][r], s[1][r]);
#pragma unroll
      for (int off = 8; off > 0; off >>= 1)
        mx = fmaxf(mx, __shfl_xor(mx, off, 16));
      float mnew = fmaxf(mrow[r], mx);
      alpha[r] = __expf(mrow[r] - mnew);
      float p0 = __expf(s[0][r] - mnew);
      float p1 = __expf(s[1][r] - mnew);
      float rs = p0 + p1;
#pragma unroll
      for (int off = 8; off > 0; off >>= 1)
        rs += __shfl_xor(rs, off, 16);
      lrow[r] = lrow[r] * alpha[r] + rs;
      mrow[r] = mnew;
      P[wave][quad * 4 + r][l15] = (__bf16)p0;
      P[wave][quad * 4 + r][16 + l15] = (__bf16)p1;
    }

    __syncthreads();  // P writes ordered before vector read
    bf16x8 pf = *(const bf16x8*)&P[wave][l15][quad * 8];
    __syncthreads();  // read complete before next iteration's writes

#pragma unroll
    for (int nt = 0; nt < 4; ++nt)
#pragma unroll
      for (int r = 0; r < 4; ++r) o[nt][r] *= alpha[r];

#pragma unroll
    for (int nt = 0; nt < 4; ++nt) {
      bf16x8 vf;
#pragma unroll
      for (int j = 0; j < 8; ++j)
        vf[j] = V[(size_t)(kb + quad * 8 + j) * DK_ + nt * 16 + l15];
      o[nt] = __builtin_amdgcn_mfma_f32_16x16x32_bf16(pf, vf, o[nt], 0, 0, 0);
    }
  }

  // ctx tile head-split, in place over this block's own Q rows
#pragma unroll
  for (int nt = 0; nt < 4; ++nt) {
#pragma unroll
    for (int r = 0; r < 4; ++r) {
      int qrow = q0 + quad * 4 + r;
      Out[(size_t)bh * S_ * DK_ + (size_t)qrow * DK_ + nt * 16 + l15] =
          (__bf16)(o[nt][r] / lrow[r]);
    }
  }
}

extern "C" void kernel_launch(void* const* d_in, const int* in_sizes, int n_in,
                              void* d_out, int out_size, void* d_ws, size_t ws_size,
                              hipStream_t stream) {
  const void* q = d_in[0];
  const void* k = d_in[1];
  const void* v = d_in[2];
  const int* mask = (const int*)d_in[3];
  const void* Wq = d_in[4];
  const void* Wk = d_in[5];
  const void* Wv = d_in[6];
  const void* Wo = d_in[7];

  const size_t NE = (size_t)B_ * H_ * S_ * DK_;  // 4,194,304 elems
  __bf16* Qh = (__bf16*)d_ws;                    // ws[0 : 8M)  -> becomes ctx
  __bf16* Kh = Qh + NE;                          // ws[8M : 16M)
  int* dflag = (int*)((char*)d_ws + 2 * NE * sizeof(__bf16));  // ws[16M]
  __bf16* Vh = (__bf16*)d_out;                   // scratch; dead before final write

  detect_dtype<<<1, 64, 0, stream>>>((const unsigned int*)q, dflag);
  dim3 g1(32, 8, 3);
  gemm3<0><<<g1, 256, 0, stream>>>(q, k, v, Wq, Wk, Wv, Qh, Kh, Vh, dflag);
  attn<<<1024, 256, 0, stream>>>(Qh, Kh, Vh, mask, Qh);
  dim3 g2(32, 8, 1);
  gemm3<1><<<g2, 256, 0, stream>>>(Qh, Qh, Qh, Wo, Wo, Wo, d_out, d_out, d_out, dflag);
}